// Round 12
// baseline (196.896 us; speedup 1.0000x reference)
//
#include <hip/hip_runtime.h>
#include <hip/hip_bf16.h>

#define NB 4
#define CCH 256
#define CRD 32
#define NN 4096

typedef __attribute__((ext_vector_type(8))) short short8;
typedef __attribute__((ext_vector_type(4))) float floatx4;
typedef __attribute__((ext_vector_type(4))) int intx4;
typedef __attribute__((ext_vector_type(2))) unsigned int uintx2;

__device__ __forceinline__ unsigned short f2bf(float f) {
  unsigned u = __builtin_bit_cast(unsigned, f);
  u += 0x7FFFu + ((u >> 16) & 1u);
  return (unsigned short)(u >> 16);
}

// Clamped convert: finite bf16 regardless of input (NaN -> -1e4 via IEEE
// maxNum/minNum). Legit qkv values |v| < ~20: transparent.
__device__ __forceinline__ unsigned short f2bf_c(float f) {
  f = fminf(fmaxf(f, -1.0e4f), 1.0e4f);
  unsigned u = __builtin_bit_cast(unsigned, f);
  u += 0x7FFFu + ((u >> 16) & 1u);
  return (unsigned short)(u >> 16);
}

__device__ __forceinline__ unsigned pack2c(float a, float b) {
  return (unsigned)f2bf_c(a) | ((unsigned)f2bf_c(b) << 16);
}

// Output sanitizer: NaN -> -1e30, +-inf -> +-1e30 (round-6/7: 0*inf = NaN).
__device__ __forceinline__ float sat(float v) {
  return fminf(fmaxf(v, -1.0e30f), 1.0e30f);
}

__device__ __forceinline__ short8 ld_frag_g(const unsigned short* p) {
  return __builtin_bit_cast(short8, *(const intx4*)p);
}

// ---------------------------------------------------------------------------
// Kernel 1: FUSED transpose + QKV GEMM.  Replaces transpose_cvt + gemm_qkv
// (the 88 us chain: xT HBM round-trip + 8-way-conflict transpose + drain).
// grid (64 n-tiles of 64, 5 mt, 4 b) = 1280 blocks (5/CU), 256 thr = 4 waves.
// Phase 1: x[b][c][ntile] fp32 -> LDS xs[n][k] bf16, 16B-unit XOR swizzle
//          (<=2-way banks, same family as attn V-staging).
// Phase 2: wave = 16 m-rows x 64 n. A-frags: W rows DIRECT from global fp32
//          (L2-resident, 128B contiguous per row), converted in-register.
//          B-frags from xs. Epilogue -> qT[b][n][32]/kT[b][n][32]/vv[b][c][n].
// ---------------------------------------------------------------------------
__global__ __launch_bounds__(256) void qkv_fused(
    const float* __restrict__ x,
    const float* __restrict__ Wq, const float* __restrict__ bq,
    const float* __restrict__ Wk, const float* __restrict__ bk,
    const float* __restrict__ Wv, const float* __restrict__ bv,
    unsigned short* __restrict__ qT, unsigned short* __restrict__ kT,
    unsigned short* __restrict__ vv)
{
  __shared__ __align__(16) unsigned char xs[64 * 512];  // 32 KiB

  const int tid = threadIdx.x;
  const int n0  = blockIdx.x << 6;
  const int mt  = blockIdx.y;   // 0..4: 0 = q+k, 1..4 = v quarter
  const int b   = blockIdx.z;

  // ---- phase 1: stage x-tile transposed (thread = one channel c = tid) ----
  {
    const float* xr = x + ((size_t)b << 20) + (size_t)tid * NN + n0;
    const int kb = tid >> 3;        // 16B unit along k
    const int ko = (tid & 7) * 2;   // byte offset within unit
#pragma unroll
    for (int j4 = 0; j4 < 16; ++j4) {
      const floatx4 f = *(const floatx4*)(xr + j4 * 4);
#pragma unroll
      for (int e = 0; e < 4; ++e) {
        const int n = j4 * 4 + e;
        *(unsigned short*)(xs + n * 512 + ((kb ^ (n & 31)) * 16) + ko) =
            f2bf(f[e]);
      }
    }
  }
  __syncthreads();

  // ---- phase 2: MFMA, wave covers 16 m-rows x 64 n ----
  const int wave = tid >> 6;
  const int lane = tid & 63;
  const int lq   = lane >> 4;
  const int lm   = lane & 15;

  const float* Wrow;
  const float* brow;
  int wl;  // A-frag row within Wrow
  if (mt == 0) {
    Wrow = (wave < 2) ? Wq : Wk;
    brow = (wave < 2) ? bq : bk;
    wl   = (wave & 1) * 16 + lm;
  } else {
    Wrow = Wv;
    brow = bv;
    wl   = (mt - 1) * 64 + wave * 16 + lm;
  }
  const float* wp = Wrow + (size_t)wl * CCH;

  floatx4 acc[4];
#pragma unroll
  for (int t = 0; t < 4; ++t) acc[t] = (floatx4){0.f, 0.f, 0.f, 0.f};

#pragma unroll
  for (int k0 = 0; k0 < 8; ++k0) {
    // A-frag: W[wl][k0*32 + lq*8 .. +8] fp32 -> bf16x8 in-register
    const floatx4 wa = *(const floatx4*)(wp + k0 * 32 + lq * 8);
    const floatx4 wb = *(const floatx4*)(wp + k0 * 32 + lq * 8 + 4);
    intx4 ai;
    ai[0] = (int)pack2c(wa[0], wa[1]);
    ai[1] = (int)pack2c(wa[2], wa[3]);
    ai[2] = (int)pack2c(wb[0], wb[1]);
    ai[3] = (int)pack2c(wb[2], wb[3]);
    const short8 af = __builtin_bit_cast(short8, ai);

    short8 bf[4];
#pragma unroll
    for (int ns = 0; ns < 4; ++ns) {
      const int n = ns * 16 + lm;
      bf[ns] = __builtin_bit_cast(
          short8,
          *(const intx4*)(xs + n * 512 + (((k0 * 4 + lq) ^ (n & 31)) * 16)));
    }
#pragma unroll
    for (int ns = 0; ns < 4; ++ns)
      acc[ns] = __builtin_amdgcn_mfma_f32_16x16x32_bf16(af, bf[ns], acc[ns],
                                                        0, 0, 0);
  }

  // ---- epilogue (C-layout: row = lq*4+r within the 16-row tile, col = lm) --
  if (mt == 0) {
    unsigned short* dst0 = (wave < 2) ? qT : kT;
    const int d0 = (wave & 1) * 16 + lq * 4;
#pragma unroll
    for (int ns = 0; ns < 4; ++ns) {
      const int n = n0 + ns * 16 + lm;
      uintx2 u;
      u[0] = pack2c(acc[ns][0] + brow[d0],     acc[ns][1] + brow[d0 + 1]);
      u[1] = pack2c(acc[ns][2] + brow[d0 + 2], acc[ns][3] + brow[d0 + 3]);
      *(uintx2*)(dst0 + (size_t)(b * NN + n) * CRD + d0) = u;
    }
  } else {
    const int cb = (mt - 1) * 64 + wave * 16 + lq * 4;
#pragma unroll
    for (int r = 0; r < 4; ++r) {
      const int c = cb + r;
      const float bvv = brow[c];
#pragma unroll
      for (int ns = 0; ns < 4; ++ns) {
        const int n = n0 + ns * 16 + lm;
        vv[(size_t)(b * CCH + c) * NN + n] = f2bf_c(acc[ns][r] + bvv);
      }
    }
  }
}

// ---------------------------------------------------------------------------
// Kernel 2: attention — UNCHANGED from round 11 (best measured 108 us):
// 512 thr, 8 waves (wg rows x cs c-half, redundant S), cross-iteration
// register prefetch of V+K, XCD swizzle (FETCH 45.6 -> 17.9 MB).
// ---------------------------------------------------------------------------
__global__ __launch_bounds__(512) void attn_kernel(
    const float* __restrict__ x, const float* __restrict__ gamma_p,
    const unsigned short* __restrict__ qT, const unsigned short* __restrict__ kT,
    const unsigned short* __restrict__ vv, float* __restrict__ out)
{
  __shared__ __align__(16) unsigned char smem[32768 + 4 * 2176];

  const int tid  = threadIdx.x;
  const int wave = tid >> 6;
  const int wg   = wave >> 1;
  const int cs   = wave & 1;
  const int lane = tid & 63;
  const int lq   = lane >> 4;
  const int lm   = lane & 15;
  const int xcd = blockIdx.x & 7;
  const int pos = blockIdx.x >> 3;
  const int b   = xcd >> 1;
  const int i0  = (((xcd & 1) << 5) | pos) << 6;

  const unsigned short* kTb = kT + (size_t)b * NN * CRD;
  const unsigned short* vb  = vv + (size_t)b * CCH * NN;
  unsigned char* pb = smem + 32768 + wg * 2176;

  const short8 qf =
      ld_frag_g(qT + (size_t)(b * NN + i0 + wg * 16 + lm) * CRD + lq * 8);

  size_t vs_g[4];
  int    vs_off[4];
#pragma unroll
  for (int m = 0; m < 4; ++m) {
    const int u  = m * 512 + tid;
    const int c  = u >> 3;
    const int jb = u & 7;
    vs_g[m]   = (size_t)c * NN + jb * 8;
    vs_off[m] = c * 128 + ((jb ^ (c & 7)) * 16);
  }

  floatx4 acc[8];
#pragma unroll
  for (int t = 0; t < 8; ++t) acc[t] = (floatx4){0.f, 0.f, 0.f, 0.f};
  float lsum[4] = {0.f, 0.f, 0.f, 0.f};

  intx4 vreg[4];
#pragma unroll
  for (int m = 0; m < 4; ++m)
    vreg[m] = *(const intx4*)(vb + vs_g[m]);
  short8 kf[4];
#pragma unroll
  for (int jt = 0; jt < 4; ++jt)
    kf[jt] = ld_frag_g(kTb + (size_t)(jt * 16 + lm) * CRD + lq * 8);

  const floatx4 zf = {0.f, 0.f, 0.f, 0.f};

#pragma unroll 1
  for (int k = 0; k < 64; ++k) {
#pragma unroll
    for (int m = 0; m < 4; ++m)
      *(intx4*)(smem + vs_off[m]) = vreg[m];

    floatx4 S[4];
#pragma unroll
    for (int jt = 0; jt < 4; ++jt) {
      S[jt] = __builtin_amdgcn_mfma_f32_16x16x32_bf16(qf, kf[jt], zf, 0, 0, 0);
#pragma unroll
      for (int r = 0; r < 4; ++r) {
        const float p = __expf(fminf(fmaxf(S[jt][r], -40.f), 40.f));
        S[jt][r] = p;
        lsum[r] += p;
      }
    }
    if (cs == 0) {
#pragma unroll
      for (int jt = 0; jt < 4; ++jt)
#pragma unroll
        for (int r = 0; r < 4; ++r)
          *(unsigned short*)(pb + (lq * 4 + r) * 136 + (jt * 16 + lm) * 2) =
              f2bf(S[jt][r]);
    }
    __syncthreads();  // A

    if (k < 63) {
      const int j0n = (k + 1) << 6;
#pragma unroll
      for (int m = 0; m < 4; ++m)
        vreg[m] = *(const intx4*)(vb + vs_g[m] + j0n);
#pragma unroll
      for (int jt = 0; jt < 4; ++jt)
        kf[jt] = ld_frag_g(kTb + (size_t)(j0n + jt * 16 + lm) * CRD + lq * 8);
    }

#pragma unroll
    for (int ks = 0; ks < 2; ++ks) {
      const unsigned char* pa = pb + lm * 136 + ks * 64 + lq * 16;
      struct U128 { unsigned long long a, b; } pp;
      pp.a = *(const unsigned long long*)pa;
      pp.b = *(const unsigned long long*)(pa + 8);
      const short8 pf = __builtin_bit_cast(short8, pp);
#pragma unroll
      for (int nt = 0; nt < 8; ++nt) {
        const int c = cs * 128 + nt * 16 + lm;
        const short8 vf = __builtin_bit_cast(
            short8,
            *(const intx4*)(smem + c * 128 + (((ks * 4 + lq) ^ (lm & 7)) * 16)));
        acc[nt] = __builtin_amdgcn_mfma_f32_16x16x32_bf16(pf, vf, acc[nt], 0, 0, 0);
      }
    }
    __syncthreads();  // B
  }

  float inv[4];
#pragma unroll
  for (int r = 0; r < 4; ++r) {
    float v = lsum[r];
    v += __shfl_xor(v, 1);
    v += __shfl_xor(v, 2);
    v += __shfl_xor(v, 4);
    v += __shfl_xor(v, 8);
    inv[r] = 1.0f / v;
  }

  const float gm = gamma_p[0];
#pragma unroll
  for (int nt = 0; nt < 8; ++nt) {
#pragma unroll
    for (int r = 0; r < 4; ++r) {
      const int c = cs * 128 + nt * 16 + lm;
      const int i = i0 + wg * 16 + lq * 4 + r;
      const size_t idx = (size_t)(b * CCH + c) * NN + i;
      out[idx] = gm * sat(acc[nt][r] * inv[r]) + x[idx];
    }
  }
}

extern "C" void kernel_launch(void* const* d_in, const int* in_sizes, int n_in,
                              void* d_out, int out_size, void* d_ws, size_t ws_size,
                              hipStream_t stream) {
  (void)in_sizes; (void)n_in; (void)out_size; (void)ws_size;
  const float* x     = (const float*)d_in[0];
  const float* Wq    = (const float*)d_in[1];
  const float* bq    = (const float*)d_in[2];
  const float* Wk    = (const float*)d_in[3];
  const float* bk    = (const float*)d_in[4];
  const float* Wv    = (const float*)d_in[5];
  const float* bv    = (const float*)d_in[6];
  const float* gamma = (const float*)d_in[7];

  unsigned short* qT = (unsigned short*)d_ws;              // 1 MiB
  unsigned short* kT = qT + (size_t)NB * NN * CRD;         // 1 MiB
  unsigned short* vv = kT + (size_t)NB * NN * CRD;         // 8 MiB

  qkv_fused<<<dim3(64, 5, 4), 256, 0, stream>>>(x, Wq, bq, Wk, bk, Wv, bv,
                                                qT, kT, vv);
  attn_kernel<<<dim3(256, 1, 1), 512, 0, stream>>>(x, gamma, qT, kT, vv,
                                                   (float*)d_out);
}